// Round 7
// baseline (359.336 us; speedup 1.0000x reference)
//
#include <hip/hip_runtime.h>
#include <hip/hip_bf16.h>

typedef __hip_bfloat16 bf16;
typedef __bf16 bf16x8 __attribute__((ext_vector_type(8)));
typedef __bf16 bf16x4 __attribute__((ext_vector_type(4)));
typedef float  f32x4  __attribute__((ext_vector_type(4)));

constexpr int NB   = 4;
constexpr int H    = 128;
constexpr int W    = 128;
constexpr int HW   = H * W;
constexpr int NPIX = NB * HW;        // 65536
constexpr int CCAT = 384;
constexpr int CSKIP= 128;
constexpr int CIN  = 256;
constexpr int CO   = 128;
constexpr int HS   = 64;
constexpr int WP   = 130;            // padded H/W
constexpr int K1   = 3456;           // conv1 GEMM K
constexpr int KD   = 1152;           // deform/off GEMM K
constexpr int NBORD= 2 * WP + 2 * (WP - 2);   // 516 border px per image
constexpr float EPS = 1e-5f;

__device__ __forceinline__ float b2f(bf16 v){ return __bfloat162float(v); }
__device__ __forceinline__ bf16  f2b(float v){ return __float2bfloat16(v); }

__device__ __forceinline__ void async_copy16(const void* g, void* s){
    __builtin_amdgcn_global_load_lds((const __attribute__((address_space(1))) void*)g,
                                     (__attribute__((address_space(3))) void*)s, 16, 0, 0);
}

// map border index 0..515 -> (y,x) on the WPxWP frame
__device__ __forceinline__ void border_yx(int p, int& y, int& x){
    if (p < WP)             { y = 0;        x = p; }
    else if (p < 2 * WP)    { y = WP - 1;   x = p - WP; }
    else if (p < 2 * WP + (WP - 2)) { y = p - 2 * WP + 1;          x = 0; }
    else                    { y = p - (2 * WP + (WP - 2)) + 1;     x = WP - 1; }
}

// ------------- prep: zero stat buffers + padded borders -------------
__global__ void k_prep(float* __restrict__ sums, bf16* __restrict__ catp,
                       bf16* __restrict__ hp){
    int i = blockIdx.x * blockDim.x + threadIdx.x;
    int stride = gridDim.x * blockDim.x;
    for (int j = i; j < 512; j += stride) sums[j] = 0.f;
    const int nCat = NB * NBORD * CCAT;
    for (int j = i; j < nCat; j += stride){
        int c = j % CCAT, r = j / CCAT, p = r % NBORD, b = r / NBORD;
        int y, x; border_yx(p, y, x);
        catp[(((size_t)b * WP + y) * WP + x) * CCAT + c] = f2b(0.f);
    }
    const int nHp = NB * NBORD * CO;
    for (int j = i; j < nHp; j += stride){
        int c = j % CO, r = j / CO, p = r % NBORD, b = r / NBORD;
        int y, x; border_yx(p, y, x);
        hp[(((size_t)b * WP + y) * WP + x) * CO + c] = f2b(0.f);
    }
}

// ------------- build cat interior via LDS transpose -------------
__global__ __launch_bounds__(256) void k_build_cat2(const float* __restrict__ x,
                                                    const float* __restrict__ skip,
                                                    bf16* __restrict__ catp){
    constexpr int TS = 66;
    __shared__ bf16 tile[128 * TS];
    int t  = threadIdx.x;
    int y  = blockIdx.x % H, b = blockIdx.x / H;
    int xx = t & 127, cp = t >> 7;

    float cy = (y * 63.0f) / 127.0f;
    int   y0 = (int)cy;
    int   y1 = min(y0 + 1, HS - 1);
    float wy = cy - y0;
    float cxf = (xx * 63.0f) / 127.0f;
    int   x0 = (int)cxf;
    int   x1 = min(x0 + 1, HS - 1);
    float wx = cxf - x0;

    bf16* orow = catp + (((size_t)b * WP + y + 1) * WP + 1) * CCAT;

    for (int chunk = 0; chunk < 6; chunk++){
        int cbase = chunk * 64;
        if (chunk >= 1) __syncthreads();
        if (chunk < 2){
            const float* sb = skip + ((size_t)(b * CSKIP + cbase + cp * 32) * H + y) * W;
#pragma unroll
            for (int i = 0; i < 32; i++)
                tile[xx * TS + cp * 32 + i] = f2b(sb[(size_t)i * HW + xx]);
        } else {
            int icb = (chunk - 2) * 64 + cp * 32;
            const float* xr0 = x + ((size_t)(b * CIN + icb) * HS + y0) * HS;
            const float* xr1 = x + ((size_t)(b * CIN + icb) * HS + y1) * HS;
#pragma unroll
            for (int i = 0; i < 32; i++){
                const float* r0 = xr0 + (size_t)i * HS * HS;
                const float* r1 = xr1 + (size_t)i * HS * HS;
                float v0 = r0[x0] * (1 - wx) + r0[x1] * wx;
                float v1 = r1[x0] * (1 - wx) + r1[x1] * wx;
                tile[xx * TS + cp * 32 + i] = f2b(v0 * (1 - wy) + v1 * wy);
            }
        }
        __syncthreads();
        int cc2 = (t & 31) * 2;
        int px0 = t >> 5;
#pragma unroll
        for (int pp = 0; pp < 16; pp++){
            int px = pp * 8 + px0;
            unsigned int v = *(const unsigned int*)&tile[px * TS + cc2];
            *(unsigned int*)&orow[(size_t)px * CCAT + cbase + cc2] = v;
        }
    }
}

// ------------- all weight transposes in one kernel -------------
__global__ void k_tr_all(const float* __restrict__ w1, const float* __restrict__ wo,
                         const float* __restrict__ wd,
                         bf16* __restrict__ wt1, bf16* __restrict__ wto,
                         bf16* __restrict__ wtd){
    int i = blockIdx.x * blockDim.x + threadIdx.x;
    if (i < CO * K1){
        int k = i % K1, oc = i / K1;
        int ky = k / 1152, r = k % 1152, kx = r / 384, ic = r % 384;
        wt1[i] = f2b(w1[((oc * CCAT + ic) * 3 + ky) * 3 + kx]);
        return;
    }
    i -= CO * K1;
    if (i < 32 * KD){
        int kk = i % KD, o = i / KD;
        int ky = kk / 384, r = kk % 384, kx = r >> 7, ic = r & 127;
        wto[i] = (o < 18) ? f2b(wo[((o * CO + ic) * 3 + ky) * 3 + kx]) : f2b(0.f);
        return;
    }
    i -= 32 * KD;
    if (i < CO * KD){
        int kk = i % KD, o = i / KD;
        int kp = kk >> 7, c = kk & 127;
        wtd[i] = f2b(wd[(o * CO + c) * 9 + kp]);
    }
}

// ------------- conv1 implicit-GEMM MFMA, M=256 (2 rows) + fused BN1 stats -------------
// 512 threads / 8 waves. Tile: 256 px (2 consecutive output rows) x 128 oc.
// Halves the structural 3x A re-fetch (4 input rows per 2 output rows).
__global__ __launch_bounds__(512) void k_conv1_mfma(const bf16* __restrict__ catp,
                                                    const bf16* __restrict__ wbt,
                                                    bf16* __restrict__ hp,
                                                    float* __restrict__ sums){
    __shared__ unsigned short Ab[256 * 64];   // 32 KB
    __shared__ unsigned short Bb[128 * 64];   // 16 KB
    __shared__ float ps[256];
    int t = threadIdx.x;
    int l = t & 63, w = t >> 6;               // w: 0..7
    int y0 = (blockIdx.x & 63) * 2, b = blockIdx.x >> 6;

    int pr   = l >> 3;
    int koct = (l & 7) ^ pr;
    int m    = l & 15, quad = l >> 4;
    int wm   = w & 3,  wn   = w >> 2;         // 4 m-subtiles x 2 n-subtiles

    f32x4 acc[4][4];
#pragma unroll
    for (int i = 0; i < 4; i++)
#pragma unroll
        for (int j = 0; j < 4; j++) acc[i][j] = f32x4{0.f, 0.f, 0.f, 0.f};

    const size_t rowStride = (size_t)WP * CCAT;
    const bf16* Abase = catp + ((size_t)(b * WP) + y0) * rowStride;  // padded row y0

    for (int ky = 0; ky < 3; ky++){
        for (int kc = 0; kc < 18; kc++){
            int c0 = kc / 6, r0 = (kc % 6) * 64;
            __syncthreads();
            // A: 256 px-rows, 4 issues/wave (8 px each; rr wave-uniform per issue)
#pragma unroll
            for (int i = 0; i < 4; i++){
                int pxg = i * 64 + w * 8;          // 0..248
                int rr  = pxg >> 7;                // output-row select (0/1)
                int xl  = (pxg & 127) + pr;        // x within 128
                const bf16* Arow = Abase + (size_t)(rr + ky) * rowStride;
                async_copy16(Arow + (size_t)(xl + c0) * CCAT + r0 + koct * 8,
                             &Ab[pxg * 64]);
            }
            int kg = ky * 1152 + kc * 64;
#pragma unroll
            for (int i = 0; i < 2; i++){
                int ocg = i * 64 + w * 8;
                async_copy16(wbt + (size_t)(ocg + pr) * K1 + kg + koct * 8,
                             &Bb[ocg * 64]);
            }
            __syncthreads();
            const bf16x8* ap = (const bf16x8*)Ab;
            const bf16x8* bp = (const bf16x8*)Bb;
#pragma unroll
            for (int ks = 0; ks < 2; ks++){
                bf16x8 af[4], bfr[4];
#pragma unroll
                for (int mi = 0; mi < 4; mi++){
                    int px = wm * 64 + mi * 16 + m;
                    af[mi] = ap[px * 8 + ((ks * 4 + quad) ^ (px & 7))];
                }
#pragma unroll
                for (int ni = 0; ni < 4; ni++){
                    int oc = wn * 64 + ni * 16 + m;
                    bfr[ni] = bp[oc * 8 + ((ks * 4 + quad) ^ (oc & 7))];
                }
#pragma unroll
                for (int mi = 0; mi < 4; mi++)
#pragma unroll
                    for (int ni = 0; ni < 4; ni++)
                        acc[mi][ni] = __builtin_amdgcn_mfma_f32_16x16x32_bf16(
                            af[mi], bfr[ni], acc[mi][ni], 0, 0, 0);
            }
        }
    }
    // epilogue: px = p0+r (0..255): row y0+(px>>7), x = px&127
#pragma unroll
    for (int mi = 0; mi < 4; mi++){
        int p0 = wm * 64 + mi * 16 + quad * 4;
        size_t obase = (((size_t)b * WP + y0 + (p0 >> 7) + 1) * WP + 1 + (p0 & 127)) * CO;
#pragma unroll
        for (int ni = 0; ni < 4; ni++){
            int oc = wn * 64 + ni * 16 + m;
#pragma unroll
            for (int r = 0; r < 4; r++)
                hp[obase + (size_t)r * CO + oc] = f2b(acc[mi][ni][r]);
        }
    }
    // fused BN1 stats (shfl quad-reduction, then LDS, then one global atomic)
    if (t < 256) ps[t] = 0.f;
    __syncthreads();
#pragma unroll
    for (int ni = 0; ni < 4; ni++){
        int ch = wn * 64 + ni * 16 + m;
        float s = 0.f, q = 0.f;
#pragma unroll
        for (int mi = 0; mi < 4; mi++)
#pragma unroll
            for (int r = 0; r < 4; r++){
                float v = acc[mi][ni][r];
                s += v; q += v * v;
            }
        s += __shfl_xor(s, 16); s += __shfl_xor(s, 32);
        q += __shfl_xor(q, 16); q += __shfl_xor(q, 32);
        if (quad == 0){
            atomicAdd(&ps[ch], s);
            atomicAdd(&ps[128 + ch], q);
        }
    }
    __syncthreads();
    if (t < 128){
        atomicAdd(&sums[t],       ps[t]);
        atomicAdd(&sums[128 + t], ps[128 + t]);
    }
}

// ------------- BN1 apply + relu in place (scale/shift computed inline) -------------
__global__ __launch_bounds__(256) void k_bn_apply_pad(bf16* __restrict__ t,
                                                      const float* __restrict__ sums,
                                                      const float* __restrict__ g,
                                                      const float* __restrict__ bb){
    __shared__ float ssc[256];
    int tt = threadIdx.x;
    if (tt < 128){
        float mean = sums[tt] / (float)NPIX;
        float var  = sums[128 + tt] / (float)NPIX - mean * mean;
        float scale = g[tt] * rsqrtf(var + EPS);
        ssc[tt]       = scale;
        ssc[128 + tt] = bb[tt] - mean * scale;
    }
    __syncthreads();
    int i = blockIdx.x * 256 + tt;
    if (i >= NPIX * CO) return;
    int c = i & 127;
    int pix = i >> 7;
    int xw = pix & 127, yh = (pix >> 7) & 127, b = pix >> 14;
    size_t a = (((size_t)b * WP + yh + 1) * WP + xw + 1) * CO + c;
    float v = b2f(t[a]) * ssc[c] + ssc[128 + c];
    t[a] = f2b(v > 0.f ? v : 0.f);
}

// ------------- offset conv as MFMA: hp -> offs[pix][18] -------------
__global__ __launch_bounds__(256) void k_conv_off_mfma(const bf16* __restrict__ hp,
                                                       const bf16* __restrict__ wob,
                                                       const float* __restrict__ off_b,
                                                       bf16* __restrict__ offs){
    __shared__ unsigned short Ab[128 * 64];
    __shared__ unsigned short Bb[32 * 64];
    int t = threadIdx.x, l = t & 63, w = t >> 6;
    int y = blockIdx.x % H, b = blockIdx.x / H;
    int pr = l >> 3, koct = (l & 7) ^ pr;
    int m = l & 15, quad = l >> 4;
    int wm = w & 1, wn = w >> 1;

    f32x4 acc[4];
#pragma unroll
    for (int i = 0; i < 4; i++) acc[i] = f32x4{0.f, 0.f, 0.f, 0.f};

    const size_t rowStride = (size_t)WP * CO;
    for (int ky = 0; ky < 3; ky++){
        const bf16* Arow = hp + ((size_t)(b * WP) + y + ky) * rowStride;
        for (int kc = 0; kc < 6; kc++){
            int kx = kc >> 1, r0 = (kc & 1) * 64;
            __syncthreads();
#pragma unroll
            for (int i = 0; i < 4; i++){
                int px = w * 32 + i * 8 + pr;
                async_copy16(Arow + (size_t)(px + kx) * CO + r0 + koct * 8,
                             &Ab[(w * 32 + i * 8) * 64]);
            }
            int kg = ky * 384 + kx * 128 + r0;
            async_copy16(wob + (size_t)(w * 8 + pr) * KD + kg + koct * 8,
                         &Bb[(w * 8) * 64]);
            __syncthreads();
            const bf16x8* ap = (const bf16x8*)Ab;
            const bf16x8* bp = (const bf16x8*)Bb;
#pragma unroll
            for (int ks = 0; ks < 2; ks++){
                int oc = wn * 16 + m;
                bf16x8 bfr = bp[oc * 8 + ((ks * 4 + quad) ^ (oc & 7))];
#pragma unroll
                for (int mi = 0; mi < 4; mi++){
                    int px = wm * 64 + mi * 16 + m;
                    bf16x8 af = ap[px * 8 + ((ks * 4 + quad) ^ (px & 7))];
                    acc[mi] = __builtin_amdgcn_mfma_f32_16x16x32_bf16(af, bfr, acc[mi], 0, 0, 0);
                }
            }
        }
    }
    int oc = wn * 16 + m;
    if (oc < 18){
        float bias = off_b[oc];
        int rowpix = b * HW + y * W;
#pragma unroll
        for (int mi = 0; mi < 4; mi++){
            int p0 = wm * 64 + mi * 16 + quad * 4;
#pragma unroll
            for (int r = 0; r < 4; r++)
                offs[(size_t)(rowpix + p0 + r) * 18 + oc] = f2b(acc[mi][r] + bias);
        }
    }
}

// ------------- deform: A-gen in LDS + MFMA GEMM + fused BN2 stats -------------
__global__ __launch_bounds__(256) void k_deform_mfma(const bf16* __restrict__ hp,
                                                     const bf16* __restrict__ offs,
                                                     const bf16* __restrict__ wdb,
                                                     const float* __restrict__ def_b,
                                                     bf16* __restrict__ y,
                                                     float* __restrict__ sums){
    __shared__ unsigned short Ab[128 * 64];
    __shared__ unsigned short Bb[128 * 64];
    __shared__ int2   sc_yx[9 * 128];
    __shared__ float4 sc_w[9 * 128];
    __shared__ float  ps[256];

    int t = threadIdx.x, l = t & 63, w = t >> 6;
    int yrow = blockIdx.x % H, b = blockIdx.x / H;
    int rowpix = b * HW + yrow * W;

    for (int idx = t; idx < 9 * 128; idx += 256){
        int kp = idx >> 7, px = idx & 127;
        float dy = b2f(offs[(size_t)(rowpix + px) * 18 + 2 * kp]);
        float dx = b2f(offs[(size_t)(rowpix + px) * 18 + 2 * kp + 1]);
        float py = yrow + (kp / 3 - 1) + dy;
        float pxx = px + (kp % 3 - 1) + dx;
        float fy = floorf(py), fx = floorf(pxx);
        float wy = py - fy, wx = pxx - fx;
        int y0 = (int)fy, x0 = (int)fx;
        bool vy0 = (y0 >= 0) && (y0 < H);
        bool vy1 = (y0 + 1 >= 0) && (y0 + 1 < H);
        bool vx0 = (x0 >= 0) && (x0 < W);
        bool vx1 = (x0 + 1 >= 0) && (x0 + 1 < W);
        int y0c = min(max(y0, 0), H - 1),     y1c = min(max(y0 + 1, 0), H - 1);
        int x0c = min(max(x0, 0), W - 1),     x1c = min(max(x0 + 1, 0), W - 1);
        sc_yx[idx] = make_int2(((y0c + 1) * WP) | (((y1c + 1) * WP) << 16),
                               (x0c + 1) | ((x1c + 1) << 16));
        sc_w[idx] = make_float4((1 - wy) * (1 - wx) * (float)(vy0 && vx0),
                                (1 - wy) * wx       * (float)(vy0 && vx1),
                                wy * (1 - wx)       * (float)(vy1 && vx0),
                                wy * wx             * (float)(vy1 && vx1));
    }
    __syncthreads();

    int pr = l >> 3, koct = (l & 7) ^ pr;
    int m = l & 15, quad = l >> 4;
    int wm = w & 1, wn = w >> 1;
    int g = l >> 4, j = l & 15;

    f32x4 acc[4][4];
#pragma unroll
    for (int i = 0; i < 4; i++)
#pragma unroll
        for (int jj = 0; jj < 4; jj++) acc[i][jj] = f32x4{0.f, 0.f, 0.f, 0.f};

    const bf16* hpb = hp + (size_t)b * WP * WP * CO;

    for (int kc = 0; kc < 18; kc++){
        int kp = kc >> 1, ch = (kc & 1) * 64;
        __syncthreads();
        int kg = kp * 128 + ch;
#pragma unroll
        for (int i = 0; i < 4; i++){
            int oc = w * 32 + i * 8 + pr;
            async_copy16(wdb + (size_t)oc * KD + kg + koct * 8,
                         &Bb[(w * 32 + i * 8) * 64]);
        }
        int cb = ch + j * 4;
#pragma unroll
        for (int p = 0; p < 8; p++){
            int px = w * 32 + g * 8 + p;
            int idx = kp * 128 + px;
            int2 yx = sc_yx[idx];
            float4 w4 = sc_w[idx];
            int r0 = yx.x & 0xffff, r1 = ((unsigned)yx.x) >> 16;
            int c0 = yx.y & 0xffff, c1 = ((unsigned)yx.y) >> 16;
            const bf16* base = hpb + cb;
            bf16x4 s00 = *(const bf16x4*)(base + (size_t)(r0 + c0) * CO);
            bf16x4 s01 = *(const bf16x4*)(base + (size_t)(r0 + c1) * CO);
            bf16x4 s10 = *(const bf16x4*)(base + (size_t)(r1 + c0) * CO);
            bf16x4 s11 = *(const bf16x4*)(base + (size_t)(r1 + c1) * CO);
            bf16x4 pv;
#pragma unroll
            for (int r = 0; r < 4; r++){
                float v = w4.x * (float)s00[r] + w4.y * (float)s01[r]
                        + w4.z * (float)s10[r] + w4.w * (float)s11[r];
                pv[r] = (__bf16)v;
            }
            int oct_sw = (j >> 1) ^ (px & 7);
            *(bf16x4*)&Ab[px * 64 + oct_sw * 8 + (j & 1) * 4] = pv;
        }
        __syncthreads();
        const bf16x8* ap = (const bf16x8*)Ab;
        const bf16x8* bp = (const bf16x8*)Bb;
#pragma unroll
        for (int ks = 0; ks < 2; ks++){
            bf16x8 af[4], bfr[4];
#pragma unroll
            for (int mi = 0; mi < 4; mi++){
                int px = wm * 64 + mi * 16 + m;
                af[mi] = ap[px * 8 + ((ks * 4 + quad) ^ (px & 7))];
            }
#pragma unroll
            for (int ni = 0; ni < 4; ni++){
                int oc = wn * 64 + ni * 16 + m;
                bfr[ni] = bp[oc * 8 + ((ks * 4 + quad) ^ (oc & 7))];
            }
#pragma unroll
            for (int mi = 0; mi < 4; mi++)
#pragma unroll
                for (int ni = 0; ni < 4; ni++)
                    acc[mi][ni] = __builtin_amdgcn_mfma_f32_16x16x32_bf16(
                        af[mi], bfr[ni], acc[mi][ni], 0, 0, 0);
        }
    }
#pragma unroll
    for (int mi = 0; mi < 4; mi++){
        int p0 = wm * 64 + mi * 16 + quad * 4;
#pragma unroll
        for (int ni = 0; ni < 4; ni++){
            int oc = wn * 64 + ni * 16 + m;
            float bias = def_b[oc];
#pragma unroll
            for (int r = 0; r < 4; r++)
                y[(size_t)(rowpix + p0 + r) * CO + oc] = f2b(acc[mi][ni][r] + bias);
        }
    }
    // fused BN2 stats (shfl quad-reduction)
    ps[t] = 0.f;
    __syncthreads();
#pragma unroll
    for (int ni = 0; ni < 4; ni++){
        int ch = wn * 64 + ni * 16 + m;
        float bias = def_b[ch];
        float s = 0.f, q = 0.f;
#pragma unroll
        for (int mi = 0; mi < 4; mi++)
#pragma unroll
            for (int r = 0; r < 4; r++){
                float v = acc[mi][ni][r] + bias;
                s += v; q += v * v;
            }
        s += __shfl_xor(s, 16); s += __shfl_xor(s, 32);
        q += __shfl_xor(q, 16); q += __shfl_xor(q, 32);
        if (quad == 0){
            atomicAdd(&ps[ch], s);
            atomicAdd(&ps[128 + ch], q);
        }
    }
    __syncthreads();
    if (t < 128){
        atomicAdd(&sums[t],       ps[t]);
        atomicAdd(&sums[128 + t], ps[128 + t]);
    }
}

// ------------- BN2 apply + relu + NHWC->NCHW (scale/shift inline) -------------
__global__ __launch_bounds__(256) void k_final(const bf16* __restrict__ yb,
                                               const float* __restrict__ sums,
                                               const float* __restrict__ g,
                                               const float* __restrict__ bb,
                                               float* __restrict__ out){
    __shared__ unsigned short tile[128 * 129];
    __shared__ float ssc[256];
    int t = threadIdx.x;
    if (t < 128){
        float mean = sums[t] / (float)NPIX;
        float var  = sums[128 + t] / (float)NPIX - mean * mean;
        float scale = g[t] * rsqrtf(var + EPS);
        ssc[t]       = scale;
        ssc[128 + t] = bb[t] - mean * scale;
    }
    int yrow = blockIdx.x % H, b = blockIdx.x / H;
    int rowbase = b * HW + yrow * W;
    const unsigned short* src = (const unsigned short*)yb;
    for (int it = 0; it < 64; it++){
        int idx = it * 256 + t;
        int c = idx & 127, px = idx >> 7;
        tile[px * 129 + c] = src[(size_t)(rowbase + px) * CO + c];
    }
    __syncthreads();
    for (int it = 0; it < 64; it++){
        int idx = it * 256 + t;
        int xw = idx & 127, o = idx >> 7;
        unsigned short u = tile[xw * 129 + o];
        float v = (float)(*(const __bf16*)&u);
        v = v * ssc[o] + ssc[128 + o];
        out[(((size_t)b * CO + o) * H + yrow) * W + xw] = v > 0.f ? v : 0.f;
    }
}

extern "C" void kernel_launch(void* const* d_in, const int* in_sizes, int n_in,
                              void* d_out, int out_size, void* d_ws, size_t ws_size,
                              hipStream_t stream){
    const float* x      = (const float*)d_in[0];
    const float* skip   = (const float*)d_in[1];
    const float* conv1w = (const float*)d_in[2];
    const float* bn1g   = (const float*)d_in[3];
    const float* bn1b   = (const float*)d_in[4];
    const float* offw   = (const float*)d_in[5];
    const float* offb   = (const float*)d_in[6];
    const float* defw   = (const float*)d_in[7];
    const float* defb   = (const float*)d_in[8];
    const float* bn2g   = (const float*)d_in[9];
    const float* bn2b   = (const float*)d_in[10];
    float* out = (float*)d_out;

    char* ws = (char*)d_ws;
    size_t off_bytes = 0;
    auto alloc = [&](size_t bytes) -> void* {
        void* p = ws + off_bytes;
        off_bytes += (bytes + 255) & ~(size_t)255;
        return p;
    };
    const size_t catp_elems = (size_t)NB * WP * WP * CCAT;
    const size_t hp_elems   = (size_t)NB * WP * WP * CO;
    bf16*  catp  = (bf16*) alloc(catp_elems * 2);            // 51.9 MB
    bf16*  hp    = (bf16*) alloc(hp_elems * 2);              // 17.3 MB
    bf16*  offs  = (bf16*) alloc((size_t)NPIX * 18 * 2);
    bf16*  yb    = (bf16*) alloc((size_t)NPIX * CO * 2);
    bf16*  wbt   = (bf16*) alloc((size_t)CO * K1 * 2);
    bf16*  wob   = (bf16*) alloc((size_t)32 * KD * 2);
    bf16*  wdb   = (bf16*) alloc((size_t)CO * KD * 2);
    float* sums  = (float*)alloc(512 * 4);
    float* sums1 = sums;
    float* sums2 = sums + 256;

    k_prep<<<1024, 256, 0, stream>>>(sums, catp, hp);

    k_build_cat2<<<NB * H, 256, 0, stream>>>(x, skip, catp);

    const int ntr = CO * K1 + 32 * KD + CO * KD;
    k_tr_all<<<(ntr + 255) / 256, 256, 0, stream>>>(conv1w, offw, defw, wbt, wob, wdb);

    k_conv1_mfma<<<NB * H / 2, 512, 0, stream>>>(catp, wbt, hp, sums1);

    k_bn_apply_pad<<<(NPIX * CO + 255) / 256, 256, 0, stream>>>(hp, sums1, bn1g, bn1b);

    k_conv_off_mfma<<<NB * H, 256, 0, stream>>>(hp, wob, offb, offs);

    k_deform_mfma<<<NB * H, 256, 0, stream>>>(hp, offs, wdb, defb, yb, sums2);

    k_final<<<NB * H, 256, 0, stream>>>(yb, sums2, bn2g, bn2b, out);
}

// Round 8
// 334.593 us; speedup vs baseline: 1.0739x; 1.0739x over previous
//
#include <hip/hip_runtime.h>
#include <hip/hip_bf16.h>

typedef __hip_bfloat16 bf16;
typedef __bf16 bf16x8 __attribute__((ext_vector_type(8)));
typedef __bf16 bf16x4 __attribute__((ext_vector_type(4)));
typedef float  f32x4  __attribute__((ext_vector_type(4)));

constexpr int NB   = 4;
constexpr int H    = 128;
constexpr int W    = 128;
constexpr int HW   = H * W;
constexpr int NPIX = NB * HW;        // 65536
constexpr int CCAT = 384;
constexpr int CSKIP= 128;
constexpr int CIN  = 256;
constexpr int CO   = 128;
constexpr int HS   = 64;
constexpr int WP   = 130;            // padded H/W
constexpr int K1   = 3456;           // conv1 GEMM K
constexpr int KD   = 1152;           // deform/off GEMM K
constexpr int NBORD= 2 * WP + 2 * (WP - 2);   // 516 border px per image
constexpr float EPS = 1e-5f;

__device__ __forceinline__ float b2f(bf16 v){ return __bfloat162float(v); }
__device__ __forceinline__ bf16  f2b(float v){ return __float2bfloat16(v); }

__device__ __forceinline__ void async_copy16(const void* g, void* s){
    __builtin_amdgcn_global_load_lds((const __attribute__((address_space(1))) void*)g,
                                     (__attribute__((address_space(3))) void*)s, 16, 0, 0);
}

// map border index 0..515 -> (y,x) on the WPxWP frame
__device__ __forceinline__ void border_yx(int p, int& y, int& x){
    if (p < WP)             { y = 0;        x = p; }
    else if (p < 2 * WP)    { y = WP - 1;   x = p - WP; }
    else if (p < 2 * WP + (WP - 2)) { y = p - 2 * WP + 1;          x = 0; }
    else                    { y = p - (2 * WP + (WP - 2)) + 1;     x = WP - 1; }
}

// ------------- prep: zero stat buffers + padded borders -------------
__global__ void k_prep(float* __restrict__ sums, bf16* __restrict__ catp,
                       bf16* __restrict__ hp){
    int i = blockIdx.x * blockDim.x + threadIdx.x;
    int stride = gridDim.x * blockDim.x;
    for (int j = i; j < 512; j += stride) sums[j] = 0.f;
    const int nCat = NB * NBORD * CCAT;
    for (int j = i; j < nCat; j += stride){
        int c = j % CCAT, r = j / CCAT, p = r % NBORD, b = r / NBORD;
        int y, x; border_yx(p, y, x);
        catp[(((size_t)b * WP + y) * WP + x) * CCAT + c] = f2b(0.f);
    }
    const int nHp = NB * NBORD * CO;
    for (int j = i; j < nHp; j += stride){
        int c = j % CO, r = j / CO, p = r % NBORD, b = r / NBORD;
        int y, x; border_yx(p, y, x);
        hp[(((size_t)b * WP + y) * WP + x) * CO + c] = f2b(0.f);
    }
}

// ------------- build cat interior via LDS transpose -------------
__global__ __launch_bounds__(256) void k_build_cat2(const float* __restrict__ x,
                                                    const float* __restrict__ skip,
                                                    bf16* __restrict__ catp){
    constexpr int TS = 66;
    __shared__ bf16 tile[128 * TS];
    int t  = threadIdx.x;
    int y  = blockIdx.x % H, b = blockIdx.x / H;
    int xx = t & 127, cp = t >> 7;

    float cy = (y * 63.0f) / 127.0f;
    int   y0 = (int)cy;
    int   y1 = min(y0 + 1, HS - 1);
    float wy = cy - y0;
    float cxf = (xx * 63.0f) / 127.0f;
    int   x0 = (int)cxf;
    int   x1 = min(x0 + 1, HS - 1);
    float wx = cxf - x0;

    bf16* orow = catp + (((size_t)b * WP + y + 1) * WP + 1) * CCAT;

    for (int chunk = 0; chunk < 6; chunk++){
        int cbase = chunk * 64;
        if (chunk >= 1) __syncthreads();
        if (chunk < 2){
            const float* sb = skip + ((size_t)(b * CSKIP + cbase + cp * 32) * H + y) * W;
#pragma unroll
            for (int i = 0; i < 32; i++)
                tile[xx * TS + cp * 32 + i] = f2b(sb[(size_t)i * HW + xx]);
        } else {
            int icb = (chunk - 2) * 64 + cp * 32;
            const float* xr0 = x + ((size_t)(b * CIN + icb) * HS + y0) * HS;
            const float* xr1 = x + ((size_t)(b * CIN + icb) * HS + y1) * HS;
#pragma unroll
            for (int i = 0; i < 32; i++){
                const float* r0 = xr0 + (size_t)i * HS * HS;
                const float* r1 = xr1 + (size_t)i * HS * HS;
                float v0 = r0[x0] * (1 - wx) + r0[x1] * wx;
                float v1 = r1[x0] * (1 - wx) + r1[x1] * wx;
                tile[xx * TS + cp * 32 + i] = f2b(v0 * (1 - wy) + v1 * wy);
            }
        }
        __syncthreads();
        int cc2 = (t & 31) * 2;
        int px0 = t >> 5;
#pragma unroll
        for (int pp = 0; pp < 16; pp++){
            int px = pp * 8 + px0;
            unsigned int v = *(const unsigned int*)&tile[px * TS + cc2];
            *(unsigned int*)&orow[(size_t)px * CCAT + cbase + cc2] = v;
        }
    }
}

// ------------- all weight transposes in one kernel -------------
__global__ void k_tr_all(const float* __restrict__ w1, const float* __restrict__ wo,
                         const float* __restrict__ wd,
                         bf16* __restrict__ wt1, bf16* __restrict__ wto,
                         bf16* __restrict__ wtd){
    int i = blockIdx.x * blockDim.x + threadIdx.x;
    if (i < CO * K1){
        int k = i % K1, oc = i / K1;
        int ky = k / 1152, r = k % 1152, kx = r / 384, ic = r % 384;
        wt1[i] = f2b(w1[((oc * CCAT + ic) * 3 + ky) * 3 + kx]);
        return;
    }
    i -= CO * K1;
    if (i < 32 * KD){
        int kk = i % KD, o = i / KD;
        int ky = kk / 384, r = kk % 384, kx = r >> 7, ic = r & 127;
        wto[i] = (o < 18) ? f2b(wo[((o * CO + ic) * 3 + ky) * 3 + kx]) : f2b(0.f);
        return;
    }
    i -= 32 * KD;
    if (i < CO * KD){
        int kk = i % KD, o = i / KD;
        int kp = kk >> 7, c = kk & 127;
        wtd[i] = f2b(wd[(o * CO + c) * 9 + kp]);
    }
}

// ------------- conv1: row-resident A staging + MFMA + fused BN1 stats -------------
// A row-chunk (132px x 128ch = 33KB) staged ONCE per (ky,ci); the 3 kx positions
// read shifted fragments from LDS. LDS[px][o] = global[px][o ^ (px&7)] via
// permuted global gather (LDS dest stays wave-uniform linear).
__global__ __launch_bounds__(256) void k_conv1_mfma(const bf16* __restrict__ catp,
                                                    const bf16* __restrict__ wbt,
                                                    bf16* __restrict__ hp,
                                                    float* __restrict__ sums){
    __shared__ unsigned short Ab[132 * 128];   // 33792 B
    __shared__ unsigned short Bb[128 * 64];    // 16384 B
    __shared__ float ps[256];
    int t = threadIdx.x;
    int l = t & 63, w = t >> 6;
    int y = blockIdx.x % H, b = blockIdx.x / H;

    int pr   = l >> 3;
    int koct = (l & 7) ^ pr;
    int m    = l & 15, quad = l >> 4;
    int wm   = w & 1,  wn   = w >> 1;

    f32x4 acc[4][4];
#pragma unroll
    for (int i = 0; i < 4; i++)
#pragma unroll
        for (int j = 0; j < 4; j++) acc[i][j] = f32x4{0.f, 0.f, 0.f, 0.f};

    const size_t rowStride = (size_t)WP * CCAT;
    for (int ky = 0; ky < 3; ky++){
        const bf16* Arow = catp + ((size_t)(b * WP) + y + ky) * rowStride;
        for (int ci = 0; ci < 3; ci++){
            __syncthreads();                       // prior readers of Ab/Bb done
            for (int i = w; i < 33; i += 4){       // A: 33 issues, once per (ky,ci)
                int G  = i * 64 + l;
                int px = G >> 4, ol = G & 15;
                int osrc = ol ^ (px & 7);
                async_copy16(Arow + (size_t)px * CCAT + ci * 128 + osrc * 8,
                             &Ab[i * 512]);
            }
            for (int kx = 0; kx < 3; kx++){
                for (int s64 = 0; s64 < 2; s64++){
                    if (kx | s64) __syncthreads(); // prior MFMA readers of Bb done
                    int kg = ky * 1152 + kx * 384 + ci * 128 + s64 * 64;
#pragma unroll
                    for (int i = 0; i < 4; i++){
                        int ocg = w * 32 + i * 8;
                        async_copy16(wbt + (size_t)(ocg + pr) * K1 + kg + koct * 8,
                                     &Bb[ocg * 64]);
                    }
                    __syncthreads();               // staging drained (A on first iter)
                    const bf16x8* ap = (const bf16x8*)Ab;
                    const bf16x8* bp = (const bf16x8*)Bb;
#pragma unroll
                    for (int ks = 0; ks < 2; ks++){
                        int s = s64 * 2 + ks;
                        bf16x8 af[4], bfr[4];
#pragma unroll
                        for (int mi = 0; mi < 4; mi++){
                            int pxk = wm * 64 + mi * 16 + m + kx;
                            af[mi] = ap[pxk * 16 + ((s * 4 + quad) ^ (pxk & 7))];
                        }
#pragma unroll
                        for (int ni = 0; ni < 4; ni++){
                            int oc = wn * 64 + ni * 16 + m;
                            bfr[ni] = bp[oc * 8 + ((ks * 4 + quad) ^ (oc & 7))];
                        }
#pragma unroll
                        for (int mi = 0; mi < 4; mi++)
#pragma unroll
                            for (int ni = 0; ni < 4; ni++)
                                acc[mi][ni] = __builtin_amdgcn_mfma_f32_16x16x32_bf16(
                                    af[mi], bfr[ni], acc[mi][ni], 0, 0, 0);
                    }
                }
            }
        }
    }
    size_t obase = (((size_t)b * WP + y + 1) * WP + 1) * CO;
#pragma unroll
    for (int mi = 0; mi < 4; mi++){
        int p0 = wm * 64 + mi * 16 + quad * 4;
#pragma unroll
        for (int ni = 0; ni < 4; ni++){
            int oc = wn * 64 + ni * 16 + m;
#pragma unroll
            for (int r = 0; r < 4; r++)
                hp[obase + (size_t)(p0 + r) * CO + oc] = f2b(acc[mi][ni][r]);
        }
    }
    // fused BN1 stats (shfl quad-reduce -> LDS -> one global atomic per ch)
    ps[t] = 0.f;
    __syncthreads();
#pragma unroll
    for (int ni = 0; ni < 4; ni++){
        int ch = wn * 64 + ni * 16 + m;
        float s = 0.f, q = 0.f;
#pragma unroll
        for (int mi = 0; mi < 4; mi++)
#pragma unroll
            for (int r = 0; r < 4; r++){
                float v = acc[mi][ni][r];
                s += v; q += v * v;
            }
        s += __shfl_xor(s, 16); s += __shfl_xor(s, 32);
        q += __shfl_xor(q, 16); q += __shfl_xor(q, 32);
        if (quad == 0){
            atomicAdd(&ps[ch], s);
            atomicAdd(&ps[128 + ch], q);
        }
    }
    __syncthreads();
    if (t < 128){
        atomicAdd(&sums[t],       ps[t]);
        atomicAdd(&sums[128 + t], ps[128 + t]);
    }
}

// ------------- BN1 apply + relu in place (scale/shift computed inline) -------------
__global__ __launch_bounds__(256) void k_bn_apply_pad(bf16* __restrict__ t,
                                                      const float* __restrict__ sums,
                                                      const float* __restrict__ g,
                                                      const float* __restrict__ bb){
    __shared__ float ssc[256];
    int tt = threadIdx.x;
    if (tt < 128){
        float mean = sums[tt] / (float)NPIX;
        float var  = sums[128 + tt] / (float)NPIX - mean * mean;
        float scale = g[tt] * rsqrtf(var + EPS);
        ssc[tt]       = scale;
        ssc[128 + tt] = bb[tt] - mean * scale;
    }
    __syncthreads();
    int i = blockIdx.x * 256 + tt;
    if (i >= NPIX * CO) return;
    int c = i & 127;
    int pix = i >> 7;
    int xw = pix & 127, yh = (pix >> 7) & 127, b = pix >> 14;
    size_t a = (((size_t)b * WP + yh + 1) * WP + xw + 1) * CO + c;
    float v = b2f(t[a]) * ssc[c] + ssc[128 + c];
    t[a] = f2b(v > 0.f ? v : 0.f);
}

// ------------- offset conv: row-resident A + per-ky B, MFMA -------------
__global__ __launch_bounds__(256) void k_conv_off_mfma(const bf16* __restrict__ hp,
                                                       const bf16* __restrict__ wob,
                                                       const float* __restrict__ off_b,
                                                       bf16* __restrict__ offs){
    __shared__ unsigned short Ab[132 * 128];   // 33792 B
    __shared__ unsigned short Bb[32 * 384];    // 24576 B
    int t = threadIdx.x, l = t & 63, w = t >> 6;
    int y = blockIdx.x % H, b = blockIdx.x / H;
    int m = l & 15, quad = l >> 4;
    int wm = w & 1, wn = w >> 1;

    f32x4 acc[4];
#pragma unroll
    for (int i = 0; i < 4; i++) acc[i] = f32x4{0.f, 0.f, 0.f, 0.f};

    const size_t rowStrideH = (size_t)WP * CO;
    for (int ky = 0; ky < 3; ky++){
        const bf16* Arow = hp + ((size_t)(b * WP) + y + ky) * rowStrideH;
        __syncthreads();
        for (int i = w; i < 33; i += 4){       // A: full hp row once per ky
            int G  = i * 64 + l;
            int px = G >> 4, ol = G & 15;
            int osrc = ol ^ (px & 7);
            async_copy16(Arow + (size_t)px * CO + osrc * 8, &Ab[i * 512]);
        }
        for (int i = w; i < 24; i += 4){       // B: 32oc x 384k for this ky
            int g  = i * 64 + l;
            int kx = g >> 9, oc = (g >> 4) & 31, ol = g & 15;
            int osrc = ol ^ (oc & 7);
            async_copy16(wob + (size_t)oc * KD + ky * 384 + kx * 128 + osrc * 8,
                         &Bb[i * 512]);
        }
        __syncthreads();
        const bf16x8* ap = (const bf16x8*)Ab;
        const bf16x8* bp = (const bf16x8*)Bb;
        for (int kx = 0; kx < 3; kx++){
#pragma unroll
            for (int s = 0; s < 4; s++){
                int oc = wn * 16 + m;
                bf16x8 bfr = bp[kx * 512 + oc * 16 + ((s * 4 + quad) ^ (oc & 7))];
#pragma unroll
                for (int mi = 0; mi < 4; mi++){
                    int pxk = wm * 64 + mi * 16 + m + kx;
                    bf16x8 af = ap[pxk * 16 + ((s * 4 + quad) ^ (pxk & 7))];
                    acc[mi] = __builtin_amdgcn_mfma_f32_16x16x32_bf16(af, bfr, acc[mi], 0, 0, 0);
                }
            }
        }
    }
    int oc = wn * 16 + m;
    if (oc < 18){
        float bias = off_b[oc];
        int rowpix = b * HW + y * W;
#pragma unroll
        for (int mi = 0; mi < 4; mi++){
            int p0 = wm * 64 + mi * 16 + quad * 4;
#pragma unroll
            for (int r = 0; r < 4; r++)
                offs[(size_t)(rowpix + p0 + r) * 18 + oc] = f2b(acc[mi][r] + bias);
        }
    }
}

// ------------- deform: A-gen in LDS + MFMA GEMM + fused BN2 stats -------------
__global__ __launch_bounds__(256) void k_deform_mfma(const bf16* __restrict__ hp,
                                                     const bf16* __restrict__ offs,
                                                     const bf16* __restrict__ wdb,
                                                     const float* __restrict__ def_b,
                                                     bf16* __restrict__ y,
                                                     float* __restrict__ sums){
    __shared__ unsigned short Ab[128 * 64];
    __shared__ unsigned short Bb[128 * 64];
    __shared__ int2   sc_yx[9 * 128];
    __shared__ float4 sc_w[9 * 128];
    __shared__ float  ps[256];

    int t = threadIdx.x, l = t & 63, w = t >> 6;
    int yrow = blockIdx.x % H, b = blockIdx.x / H;
    int rowpix = b * HW + yrow * W;

    for (int idx = t; idx < 9 * 128; idx += 256){
        int kp = idx >> 7, px = idx & 127;
        float dy = b2f(offs[(size_t)(rowpix + px) * 18 + 2 * kp]);
        float dx = b2f(offs[(size_t)(rowpix + px) * 18 + 2 * kp + 1]);
        float py = yrow + (kp / 3 - 1) + dy;
        float pxx = px + (kp % 3 - 1) + dx;
        float fy = floorf(py), fx = floorf(pxx);
        float wy = py - fy, wx = pxx - fx;
        int y0 = (int)fy, x0 = (int)fx;
        bool vy0 = (y0 >= 0) && (y0 < H);
        bool vy1 = (y0 + 1 >= 0) && (y0 + 1 < H);
        bool vx0 = (x0 >= 0) && (x0 < W);
        bool vx1 = (x0 + 1 >= 0) && (x0 + 1 < W);
        int y0c = min(max(y0, 0), H - 1),     y1c = min(max(y0 + 1, 0), H - 1);
        int x0c = min(max(x0, 0), W - 1),     x1c = min(max(x0 + 1, 0), W - 1);
        sc_yx[idx] = make_int2(((y0c + 1) * WP) | (((y1c + 1) * WP) << 16),
                               (x0c + 1) | ((x1c + 1) << 16));
        sc_w[idx] = make_float4((1 - wy) * (1 - wx) * (float)(vy0 && vx0),
                                (1 - wy) * wx       * (float)(vy0 && vx1),
                                wy * (1 - wx)       * (float)(vy1 && vx0),
                                wy * wx             * (float)(vy1 && vx1));
    }
    __syncthreads();

    int pr = l >> 3, koct = (l & 7) ^ pr;
    int m = l & 15, quad = l >> 4;
    int wm = w & 1, wn = w >> 1;
    int g = l >> 4, j = l & 15;

    f32x4 acc[4][4];
#pragma unroll
    for (int i = 0; i < 4; i++)
#pragma unroll
        for (int jj = 0; jj < 4; jj++) acc[i][jj] = f32x4{0.f, 0.f, 0.f, 0.f};

    const bf16* hpb = hp + (size_t)b * WP * WP * CO;

    for (int kc = 0; kc < 18; kc++){
        int kp = kc >> 1, ch = (kc & 1) * 64;
        __syncthreads();
        int kg = kp * 128 + ch;
#pragma unroll
        for (int i = 0; i < 4; i++){
            int oc = w * 32 + i * 8 + pr;
            async_copy16(wdb + (size_t)oc * KD + kg + koct * 8,
                         &Bb[(w * 32 + i * 8) * 64]);
        }
        int cb = ch + j * 4;
#pragma unroll
        for (int p = 0; p < 8; p++){
            int px = w * 32 + g * 8 + p;
            int idx = kp * 128 + px;
            int2 yx = sc_yx[idx];
            float4 w4 = sc_w[idx];
            int r0 = yx.x & 0xffff, r1 = ((unsigned)yx.x) >> 16;
            int c0 = yx.y & 0xffff, c1 = ((unsigned)yx.y) >> 16;
            const bf16* base = hpb + cb;
            bf16x4 s00 = *(const bf16x4*)(base + (size_t)(r0 + c0) * CO);
            bf16x4 s01 = *(const bf16x4*)(base + (size_t)(r0 + c1) * CO);
            bf16x4 s10 = *(const bf16x4*)(base + (size_t)(r1 + c0) * CO);
            bf16x4 s11 = *(const bf16x4*)(base + (size_t)(r1 + c1) * CO);
            bf16x4 pv;
#pragma unroll
            for (int r = 0; r < 4; r++){
                float v = w4.x * (float)s00[r] + w4.y * (float)s01[r]
                        + w4.z * (float)s10[r] + w4.w * (float)s11[r];
                pv[r] = (__bf16)v;
            }
            int oct_sw = (j >> 1) ^ (px & 7);
            *(bf16x4*)&Ab[px * 64 + oct_sw * 8 + (j & 1) * 4] = pv;
        }
        __syncthreads();
        const bf16x8* ap = (const bf16x8*)Ab;
        const bf16x8* bp = (const bf16x8*)Bb;
#pragma unroll
        for (int ks = 0; ks < 2; ks++){
            bf16x8 af[4], bfr[4];
#pragma unroll
            for (int mi = 0; mi < 4; mi++){
                int px = wm * 64 + mi * 16 + m;
                af[mi] = ap[px * 8 + ((ks * 4 + quad) ^ (px & 7))];
            }
#pragma unroll
            for (int ni = 0; ni < 4; ni++){
                int oc = wn * 64 + ni * 16 + m;
                bfr[ni] = bp[oc * 8 + ((ks * 4 + quad) ^ (oc & 7))];
            }
#pragma unroll
            for (int mi = 0; mi < 4; mi++)
#pragma unroll
                for (int ni = 0; ni < 4; ni++)
                    acc[mi][ni] = __builtin_amdgcn_mfma_f32_16x16x32_bf16(
                        af[mi], bfr[ni], acc[mi][ni], 0, 0, 0);
        }
    }
#pragma unroll
    for (int mi = 0; mi < 4; mi++){
        int p0 = wm * 64 + mi * 16 + quad * 4;
#pragma unroll
        for (int ni = 0; ni < 4; ni++){
            int oc = wn * 64 + ni * 16 + m;
            float bias = def_b[oc];
#pragma unroll
            for (int r = 0; r < 4; r++)
                y[(size_t)(rowpix + p0 + r) * CO + oc] = f2b(acc[mi][ni][r] + bias);
        }
    }
    // fused BN2 stats (shfl quad-reduction)
    ps[t] = 0.f;
    __syncthreads();
#pragma unroll
    for (int ni = 0; ni < 4; ni++){
        int ch = wn * 64 + ni * 16 + m;
        float bias = def_b[ch];
        float s = 0.f, q = 0.f;
#pragma unroll
        for (int mi = 0; mi < 4; mi++)
#pragma unroll
            for (int r = 0; r < 4; r++){
                float v = acc[mi][ni][r] + bias;
                s += v; q += v * v;
            }
        s += __shfl_xor(s, 16); s += __shfl_xor(s, 32);
        q += __shfl_xor(q, 16); q += __shfl_xor(q, 32);
        if (quad == 0){
            atomicAdd(&ps[ch], s);
            atomicAdd(&ps[128 + ch], q);
        }
    }
    __syncthreads();
    if (t < 128){
        atomicAdd(&sums[t],       ps[t]);
        atomicAdd(&sums[128 + t], ps[128 + t]);
    }
}

// ------------- BN2 apply + relu + NHWC->NCHW (scale/shift inline) -------------
__global__ __launch_bounds__(256) void k_final(const bf16* __restrict__ yb,
                                               const float* __restrict__ sums,
                                               const float* __restrict__ g,
                                               const float* __restrict__ bb,
                                               float* __restrict__ out){
    __shared__ unsigned short tile[128 * 129];
    __shared__ float ssc[256];
    int t = threadIdx.x;
    if (t < 128){
        float mean = sums[t] / (float)NPIX;
        float var  = sums[128 + t] / (float)NPIX - mean * mean;
        float scale = g[t] * rsqrtf(var + EPS);
        ssc[t]       = scale;
        ssc[128 + t] = bb[t] - mean * scale;
    }
    int yrow = blockIdx.x % H, b = blockIdx.x / H;
    int rowbase = b * HW + yrow * W;
    const unsigned short* src = (const unsigned short*)yb;
    for (int it = 0; it < 64; it++){
        int idx = it * 256 + t;
        int c = idx & 127, px = idx >> 7;
        tile[px * 129 + c] = src[(size_t)(rowbase + px) * CO + c];
    }
    __syncthreads();
    for (int it = 0; it < 64; it++){
        int idx = it * 256 + t;
        int xw = idx & 127, o = idx >> 7;
        unsigned short u = tile[xw * 129 + o];
        float v = (float)(*(const __bf16*)&u);
        v = v * ssc[o] + ssc[128 + o];
        out[(((size_t)b * CO + o) * H + yrow) * W + xw] = v > 0.f ? v : 0.f;
    }
}

extern "C" void kernel_launch(void* const* d_in, const int* in_sizes, int n_in,
                              void* d_out, int out_size, void* d_ws, size_t ws_size,
                              hipStream_t stream){
    const float* x      = (const float*)d_in[0];
    const float* skip   = (const float*)d_in[1];
    const float* conv1w = (const float*)d_in[2];
    const float* bn1g   = (const float*)d_in[3];
    const float* bn1b   = (const float*)d_in[4];
    const float* offw   = (const float*)d_in[5];
    const float* offb   = (const float*)d_in[6];
    const float* defw   = (const float*)d_in[7];
    const float* defb   = (const float*)d_in[8];
    const float* bn2g   = (const float*)d_in[9];
    const float* bn2b   = (const float*)d_in[10];
    float* out = (float*)d_out;

    char* ws = (char*)d_ws;
    size_t off_bytes = 0;
    auto alloc = [&](size_t bytes) -> void* {
        void* p = ws + off_bytes;
        off_bytes += (bytes + 255) & ~(size_t)255;
        return p;
    };
    const size_t catp_elems = (size_t)NB * WP * WP * CCAT;
    const size_t hp_elems   = (size_t)NB * WP * WP * CO;
    bf16*  catp  = (bf16*) alloc(catp_elems * 2);            // 51.9 MB
    bf16*  hp    = (bf16*) alloc(hp_elems * 2);              // 17.3 MB
    bf16*  offs  = (bf16*) alloc((size_t)NPIX * 18 * 2);
    bf16*  yb    = (bf16*) alloc((size_t)NPIX * CO * 2);
    bf16*  wbt   = (bf16*) alloc((size_t)CO * K1 * 2);
    bf16*  wob   = (bf16*) alloc((size_t)32 * KD * 2);
    bf16*  wdb   = (bf16*) alloc((size_t)CO * KD * 2);
    float* sums  = (float*)alloc(512 * 4);
    float* sums1 = sums;
    float* sums2 = sums + 256;

    k_prep<<<1024, 256, 0, stream>>>(sums, catp, hp);

    k_build_cat2<<<NB * H, 256, 0, stream>>>(x, skip, catp);

    const int ntr = CO * K1 + 32 * KD + CO * KD;
    k_tr_all<<<(ntr + 255) / 256, 256, 0, stream>>>(conv1w, offw, defw, wbt, wob, wdb);

    k_conv1_mfma<<<NB * H, 256, 0, stream>>>(catp, wbt, hp, sums1);

    k_bn_apply_pad<<<(NPIX * CO + 255) / 256, 256, 0, stream>>>(hp, sums1, bn1g, bn1b);

    k_conv_off_mfma<<<NB * H, 256, 0, stream>>>(hp, wob, offb, offs);

    k_deform_mfma<<<NB * H, 256, 0, stream>>>(hp, offs, wdb, defb, yb, sums2);

    k_final<<<NB * H, 256, 0, stream>>>(yb, sums2, bn2g, bn2b, out);
}